// Round 18
// baseline (543.004 us; speedup 1.0000x reference)
//
#include <hip/hip_runtime.h>
#include <hip/hip_bf16.h>

#define BB 256
#define TT 512
#define EE 300
#define G4 200     // 4*H1
#define NPAD 208   // padded gate dim (13*16)
#define KP 1216    // proj split K'
#define KC 64
#define KPD (KP/2)
#define KCD (KC/2)
#define NCH 19
#define NT 13
#define BOFF 8192
#define BUFB 34816

typedef __attribute__((ext_vector_type(8))) short short8v;
typedef __attribute__((ext_vector_type(4))) float float4v;
typedef __attribute__((ext_vector_type(4))) unsigned int uint4v;

// permuted gate col: G1 column jp corresponds to W row (jp&3)*50 + (jp>>2),
// i.e. jp = 4u+g holds gate g of unit u.

__device__ __forceinline__ float sigm(float x) {
    return __builtin_amdgcn_rcpf(1.f + __builtin_amdgcn_exp2f(-1.442695040888963f * x));
}
__device__ __forceinline__ float tanh_(float x) {
    float t = __builtin_amdgcn_exp2f(2.885390081777927f * x);   // e^(2x)
    return 1.f - 2.f * __builtin_amdgcn_rcpf(t + 1.f);
}

// split a into bf16 hi/lo (RNE): a ~= hi + lo, err ~2^-16 rel
__device__ __forceinline__ uint2 bfsplit(float a) {
    unsigned u = __float_as_uint(a);
    unsigned rh = (u + 0x7FFFu + ((u >> 16) & 1u)) & 0xFFFF0000u;
    float l = a - __uint_as_float(rh);
    unsigned v = __float_as_uint(l);
    unsigned rl = (v + 0x7FFFu + ((v >> 16) & 1u)) >> 16;
    return make_uint2(rh >> 16, rl);
}

// ---------------------------------------------------------------------------
// K1: proj weights: split-bf16 B' [NPAD][KP] + permuted bias
__global__ void wtrans_kernel(const float* __restrict__ W, const float* __restrict__ b1,
                              unsigned* __restrict__ Btg, float* __restrict__ b1p) {
    int e = blockIdx.x;
    int j = threadIdx.x;
    if (j >= NPAD) return;
    float w = 0.f;
    if (j < G4) w = W[((j & 3) * 50 + (j >> 2)) * EE + e];
    uint2 s = bfsplit(w);
    *(uint2*)(Btg + (size_t)j * KPD + 2 * e) =
        make_uint2(s.x | (s.x << 16), s.y | (s.y << 16));
    if (e == 0) b1p[j] = (j < G4) ? b1[(j & 3) * 50 + (j >> 2)] : 0.f;
}

// ---------------------------------------------------------------------------
// K2: MFMA proj — R16-verified version (256 thr, 4 waves, ~85us). UNCHANGED.
__global__ __launch_bounds__(256, 2) void proj_kernel(
    const int* __restrict__ x, const int* __restrict__ lengths,
    const float* __restrict__ emb, const unsigned* __restrict__ Btg,
    const float* __restrict__ b1p, float* __restrict__ G1, int b0)
{
    const int b  = b0 + blockIdx.y;
    const int t0 = blockIdx.x * 64;
    const int len = lengths[b];
    if (t0 >= len) return;

    const int tid  = threadIdx.x;
    const int wv   = tid >> 6;
    const int lane = tid & 63;

    __shared__ __align__(16) char lds[2 * BUFB];

    const int arow = tid >> 2;
    const int ag   = tid & 3;
    const float* er = emb + (size_t)x[b * TT + t0 + arow] * EE;

    float4v acc[NT] = {};

    auto stageB = [&](int c, int q) {
        char* base = lds + q * BUFB + BOFF;
        #pragma unroll
        for (int rr = 0; rr < 7; ++rr) {
            if (rr < 6 || tid < 128) {
                int g   = rr * 256 + tid;
                int row = g >> 3, sl = g & 7;
                const unsigned* src = Btg + (size_t)row * KPD + c * KCD
                                      + ((sl ^ (row & 7)) << 2);
                char* dst = base + (rr * 256 + (tid & ~63)) * 16;
                __builtin_amdgcn_global_load_lds(
                    (const __attribute__((address_space(1))) void*)src,
                    (__attribute__((address_space(3))) void*)dst, 16, 0, 0);
            }
        }
    };
    auto loadA = [&](int cc) -> float4 {
        int k0 = cc * 16 + ag * 4;
        if (k0 < EE) return *(const float4*)(er + k0);
        return make_float4(0.f, 0.f, 0.f, 0.f);
    };
    auto writeA = [&](int q, float4 av) {
        uint2 s0 = bfsplit(av.x), s1 = bfsplit(av.y);
        uint2 s2 = bfsplit(av.z), s3 = bfsplit(av.w);
        unsigned p0 = s0.x | (s0.y << 16), p1 = s1.x | (s1.y << 16);
        unsigned p2 = s2.x | (s2.y << 16), p3 = s3.x | (s3.y << 16);
        char* base = lds + q * BUFB + (arow << 7);
        int r7 = arow & 7;
        *(uint4v*)(base + ((( 2 * ag    ) ^ r7) << 4)) = uint4v{p0, p0, p1, p1};
        *(uint4v*)(base + (((2 * ag + 1) ^ r7) << 4)) = uint4v{p2, p2, p3, p3};
    };

    stageB(0, 0);
    float4 aval = loadA(0);
    asm volatile("s_waitcnt vmcnt(0)" ::: "memory");
    writeA(0, aval);
    asm volatile("s_waitcnt lgkmcnt(0)" ::: "memory");
    __builtin_amdgcn_s_barrier();
    __builtin_amdgcn_sched_barrier(0);

    int p = 0;
    for (int c = 0; c < NCH; ++c) {
        const int q = p ^ 1;
        if (c + 1 < NCH) {
            stageB(c + 1, q);
            aval = loadA(c + 1);
        }
        const int r  = lane & 15;
        const int h  = lane >> 4;
        #pragma unroll
        for (int s = 0; s < 2; ++s) {
            const int sw4 = (((4 * s + h) ^ (r & 7)) << 4);
            short8v aF = *(const short8v*)(lds + p * BUFB + ((wv * 16 + r) << 7) + sw4);
            #pragma unroll
            for (int nt = 0; nt < NT; ++nt) {
                short8v bF = *(const short8v*)(lds + p * BUFB + BOFF
                                               + ((nt * 16 + r) << 7) + sw4);
                acc[nt] = __builtin_amdgcn_mfma_f32_16x16x32_bf16(aF, bF, acc[nt], 0, 0, 0);
            }
        }
        if (c + 1 < NCH) {
            asm volatile("s_waitcnt vmcnt(0)" ::: "memory");
            writeA(q, aval);
            asm volatile("s_waitcnt lgkmcnt(0)" ::: "memory");
            __builtin_amdgcn_s_barrier();
            __builtin_amdgcn_sched_barrier(0);
        }
        p = q;
    }

    float* gbase = G1 + ((size_t)blockIdx.y * TT + t0) * G4;
    const int col = lane & 15, rq = lane >> 4;
    #pragma unroll
    for (int nt = 0; nt < NT; ++nt) {
        int jp = nt * 16 + col;
        if (jp < G4) {
            float bias = b1p[jp];
            #pragma unroll
            for (int rr = 0; rr < 4; ++rr)
                gbase[(size_t)(wv * 16 + rq * 4 + rr) * G4 + jp] = acc[nt][rr] + bias;
        }
    }
}

// ---------------------------------------------------------------------------
// K3: recurrence — ZERO-BARRIER single-wave-per-element.
// 64-thread blocks (1 wave). Lane u = unit u: 0..49 LSTM1, 50..59 LSTM2
// (one-step lag), 60..63 idle. Each lane holds ALL 4 gate weight rows,
// zero-padded to the 64-float h-vector layout: h1 at [0..49], h2 at [52..61].
// Per step: 16 broadcast ds_read_b128 of h, 256 in-lane FMA, lane-local cell
// update, 1 ds_write_b32, 1 lgkmcnt(0). No s_barrier, no cross-lane ops.
__global__ __launch_bounds__(64, 1) void lstm_kernel(
    const int* __restrict__ lengths,
    const float* __restrict__ W_hh1, const float* __restrict__ W_ih2,
    const float* __restrict__ W_hh2, const float* __restrict__ b2,
    const float* __restrict__ fc1w, const float* __restrict__ fc1b,
    const float* __restrict__ fc2w, const float* __restrict__ fc2b,
    const float* __restrict__ G1, float* __restrict__ out, int b0)
{
    const int bb = blockIdx.x;
    const int b  = b0 + bb;
    const int u  = threadIdx.x;          // 0..63
    const int len = lengths[b];

    __shared__ __align__(16) float hs[2][64];
    __shared__ float hfin[12];
    __shared__ float zbuf[12];

    hs[0][u] = 0.f;
    hs[1][u] = 0.f;

    const bool isL1 = (u < 50);
    const bool isL2 = (u >= 50 && u < 60);

    // ---- weights: w[g][m] = float4 chunk m of padded-64 row for gate g
    float4 w[4][16];
    #pragma unroll
    for (int g = 0; g < 4; ++g)
        #pragma unroll
        for (int m = 0; m < 16; ++m)
            w[g][m] = make_float4(0.f, 0.f, 0.f, 0.f);

    if (isL1) {
        #pragma unroll
        for (int g = 0; g < 4; ++g) {
            const float* wp = W_hh1 + (g * 50 + u) * 50;
            #pragma unroll
            for (int m = 0; m < 12; ++m)
                w[g][m] = make_float4(wp[4*m], wp[4*m+1], wp[4*m+2], wp[4*m+3]);
            w[g][12].x = wp[48];
            w[g][12].y = wp[49];
        }
    } else if (isL2) {
        #pragma unroll
        for (int g = 0; g < 4; ++g) {
            int row = g * 10 + (u - 50);
            const float* wp = W_ih2 + row * 50;
            #pragma unroll
            for (int m = 0; m < 12; ++m)
                w[g][m] = make_float4(wp[4*m], wp[4*m+1], wp[4*m+2], wp[4*m+3]);
            w[g][12].x = wp[48];
            w[g][12].y = wp[49];
            const float* wq = W_hh2 + row * 10;      // h2 slots 52..61
            w[g][13] = make_float4(wq[0], wq[1], wq[2], wq[3]);
            w[g][14] = make_float4(wq[4], wq[5], wq[6], wq[7]);
            w[g][15].x = wq[8];
            w[g][15].y = wq[9];
        }
    }

    // ---- per-lane gate bases: L1 from G1 (prefetched), L2 from b2
    float4 bb4 = make_float4(0.f, 0.f, 0.f, 0.f);
    if (isL2) {
        int u2 = u - 50;
        bb4 = make_float4(b2[u2], b2[10 + u2], b2[20 + u2], b2[30 + u2]);
    }

    const float* g1p = G1 + (size_t)bb * TT * G4 + (isL1 ? 4 * u : 0);
    float4 f0, f1, f2;                    // 3-deep G1 prefetch
    {
        int t1 = (1 < len) ? 1 : len - 1;
        int t2 = (2 < len) ? 2 : len - 1;
        f0 = *(const float4*)(g1p);
        f1 = *(const float4*)(g1p + (size_t)t1 * G4);
        f2 = *(const float4*)(g1p + (size_t)t2 * G4);
    }

    const int  slot = isL1 ? u : (52 + (u - 50));
    const bool wr   = (u < 60);

    float c = 0.f, hkeep = 0.f;
    asm volatile("s_waitcnt lgkmcnt(0)" ::: "memory");   // hs zero-init visible

    for (int i = 0; i < len; ++i) {
        float4 gb = isL1 ? f0 : bb4;
        f0 = f1; f1 = f2;
        int tn = (i + 3 < len) ? i + 3 : len - 1;
        f2 = *(const float4*)(g1p + (size_t)tn * G4);   // stays in flight

        float a0 = gb.x, a1 = gb.y, a2 = gb.z, a3 = gb.w;
        const float* hb = hs[i & 1];
        #pragma unroll
        for (int m = 0; m < 16; ++m) {
            float4 hv = *(const float4*)(hb + 4 * m);
            a0 = fmaf(w[0][m].x, hv.x, a0);
            a1 = fmaf(w[1][m].x, hv.x, a1);
            a2 = fmaf(w[2][m].x, hv.x, a2);
            a3 = fmaf(w[3][m].x, hv.x, a3);
            a0 = fmaf(w[0][m].y, hv.y, a0);
            a1 = fmaf(w[1][m].y, hv.y, a1);
            a2 = fmaf(w[2][m].y, hv.y, a2);
            a3 = fmaf(w[3][m].y, hv.y, a3);
            a0 = fmaf(w[0][m].z, hv.z, a0);
            a1 = fmaf(w[1][m].z, hv.z, a1);
            a2 = fmaf(w[2][m].z, hv.z, a2);
            a3 = fmaf(w[3][m].z, hv.z, a3);
            a0 = fmaf(w[0][m].w, hv.w, a0);
            a1 = fmaf(w[1][m].w, hv.w, a1);
            a2 = fmaf(w[2][m].w, hv.w, a2);
            a3 = fmaf(w[3][m].w, hv.w, a3);
        }

        // lane-local cell update (gates i,f,g,o = a0..a3)
        float cn = sigm(a1) * c + sigm(a0) * tanh_(a2);
        float hn = sigm(a3) * tanh_(cn);
        if (isL2 && i == 0) { cn = 0.f; hn = 0.f; }     // L2 lag: h2(-1)=0
        c = cn;
        hkeep = hn;
        if (wr) hs[(i & 1) ^ 1][slot] = hn;             // write next buffer

        asm volatile("s_waitcnt lgkmcnt(0)" ::: "memory");  // write visible
    }

    // ---- tail: L2 computes h2(len-1) from buffer len&1 = {h1(len-1), h2(len-2)}
    {
        float a0 = bb4.x, a1 = bb4.y, a2 = bb4.z, a3 = bb4.w;
        const float* hb = hs[len & 1];
        #pragma unroll
        for (int m = 0; m < 16; ++m) {
            float4 hv = *(const float4*)(hb + 4 * m);
            a0 = fmaf(w[0][m].x, hv.x, a0);
            a1 = fmaf(w[1][m].x, hv.x, a1);
            a2 = fmaf(w[2][m].x, hv.x, a2);
            a3 = fmaf(w[3][m].x, hv.x, a3);
            a0 = fmaf(w[0][m].y, hv.y, a0);
            a1 = fmaf(w[1][m].y, hv.y, a1);
            a2 = fmaf(w[2][m].y, hv.y, a2);
            a3 = fmaf(w[3][m].y, hv.y, a3);
            a0 = fmaf(w[0][m].z, hv.z, a0);
            a1 = fmaf(w[1][m].z, hv.z, a1);
            a2 = fmaf(w[2][m].z, hv.z, a2);
            a3 = fmaf(w[3][m].z, hv.z, a3);
            a0 = fmaf(w[0][m].w, hv.w, a0);
            a1 = fmaf(w[1][m].w, hv.w, a1);
            a2 = fmaf(w[2][m].w, hv.w, a2);
            a3 = fmaf(w[3][m].w, hv.w, a3);
        }
        float cn = sigm(a1) * c + sigm(a0) * tanh_(a2);
        float hn = sigm(a3) * tanh_(cn);
        if (isL2) hfin[u - 50] = hn;
    }
    asm volatile("s_waitcnt lgkmcnt(0)" ::: "memory");

    // ---- MLP head (single wave: lgkm waits only)
    if (u < 10) {
        float s = fc1b[u];
        #pragma unroll
        for (int k = 0; k < 10; ++k) s = fmaf(fc1w[u * 10 + k], hfin[k], s);
        zbuf[u] = s > 0.f ? s : 0.f;
    }
    asm volatile("s_waitcnt lgkmcnt(0)" ::: "memory");
    if (u == 0) {
        float s = fc2b[0];
        #pragma unroll
        for (int k = 0; k < 10; ++k) s = fmaf(fc2w[k], zbuf[k], s);
        out[b] = s;
    }
}

// ---------------------------------------------------------------------------
extern "C" void kernel_launch(void* const* d_in, const int* in_sizes, int n_in,
                              void* d_out, int out_size, void* d_ws, size_t ws_size,
                              hipStream_t stream)
{
    const int*   x     = (const int*)  d_in[0];
    const int*   len   = (const int*)  d_in[1];
    const float* emb   = (const float*)d_in[2];
    const float* W_ih1 = (const float*)d_in[3];
    const float* W_hh1 = (const float*)d_in[4];
    const float* b1    = (const float*)d_in[5];
    const float* W_ih2 = (const float*)d_in[6];
    const float* W_hh2 = (const float*)d_in[7];
    const float* b2    = (const float*)d_in[8];
    const float* fc1w  = (const float*)d_in[9];
    const float* fc1b  = (const float*)d_in[10];
    const float* fc2w  = (const float*)d_in[11];
    const float* fc2b  = (const float*)d_in[12];
    float* out = (float*)d_out;

    const size_t btg_bytes = (size_t)NPAD * KPD * sizeof(unsigned);   // 505856
    const size_t b1p_off = btg_bytes;
    const size_t head = (b1p_off + NPAD * sizeof(float) + 255) & ~255ull;
    const size_t per_b = (size_t)TT * G4 * sizeof(float);             // 409600

    unsigned* Btg = (unsigned*)d_ws;
    float*    b1p = (float*)((char*)d_ws + b1p_off);
    float*    G1  = (float*)((char*)d_ws + head);

    size_t avail = ws_size > head ? ws_size - head : 0;
    int chunk = (int)(avail / per_b);
    if (chunk < 1) chunk = 1;
    if (chunk > BB) chunk = BB;

    wtrans_kernel<<<dim3(EE), dim3(256), 0, stream>>>(W_ih1, b1, Btg, b1p);

    for (int b0 = 0; b0 < BB; b0 += chunk) {
        int nb = (BB - b0) < chunk ? (BB - b0) : chunk;
        proj_kernel<<<dim3(TT / 64, nb), dim3(256), 0, stream>>>(
            x, len, emb, Btg, b1p, G1, b0);
        lstm_kernel<<<dim3(nb), dim3(64), 0, stream>>>(
            len, W_hh1, W_ih2, W_hh2, b2, fc1w, fc1b, fc2w, fc2b, G1, out, b0);
    }
}

// Round 19
// 315.374 us; speedup vs baseline: 1.7218x; 1.7218x over previous
//
#include <hip/hip_runtime.h>
#include <hip/hip_bf16.h>

#define BB 256
#define TT 512
#define EE 300
#define G4 200     // 4*H1
#define NPAD 208   // padded gate dim (13*16)
#define KP 1216    // proj split K'
#define KC 64
#define KPD (KP/2)
#define KCD (KC/2)
#define NCH 19
#define NT 13
#define BOFF 8192
#define BUFB 34816

typedef __attribute__((ext_vector_type(8))) short short8v;
typedef __attribute__((ext_vector_type(4))) float float4v;
typedef __attribute__((ext_vector_type(4))) unsigned int uint4v;

// permuted gate col: G1 column jp corresponds to W row (jp&3)*50 + (jp>>2).

__device__ __forceinline__ float sigm(float x) {
    return __builtin_amdgcn_rcpf(1.f + __builtin_amdgcn_exp2f(-1.442695040888963f * x));
}
__device__ __forceinline__ float tanh_(float x) {
    float t = __builtin_amdgcn_exp2f(2.885390081777927f * x);   // e^(2x)
    return 1.f - 2.f * __builtin_amdgcn_rcpf(t + 1.f);
}
// DPP helpers. row_shr:N = lane i reads lane i-N; row_shl:N = lane i reads
// lane i+N (16-lane rows, bound_ctrl zeros OOB/disabled sources).
template <int C>
__device__ __forceinline__ float qb(float v) {
    return __int_as_float(__builtin_amdgcn_mov_dpp(__float_as_int(v), C, 0xF, 0xF, true));
}
template <int CTRL>
__device__ __forceinline__ float dppmov(float v) {
    return __int_as_float(__builtin_amdgcn_mov_dpp(__float_as_int(v), CTRL, 0xF, 0xF, true));
}
// xor-4 pair combine, exec-safe (R16-verified): both DPP movs unconditional
// (full EXEC), pinned by asm volatile so the scheduler cannot sink them into
// the select's divergent arms; select is a value cndmask, no control flow.
__device__ __forceinline__ float xor4_sum(float t, int half) {
    float up = dppmov<0x104>(t);   // row_shl:4 -> reads lane+4
    float dn = dppmov<0x114>(t);   // row_shr:4 -> reads lane-4
    asm volatile("" : "+v"(up), "+v"(dn));
    return t + (half ? dn : up);
}

// split a into bf16 hi/lo (RNE): a ~= hi + lo, err ~2^-16 rel
__device__ __forceinline__ uint2 bfsplit(float a) {
    unsigned u = __float_as_uint(a);
    unsigned rh = (u + 0x7FFFu + ((u >> 16) & 1u)) & 0xFFFF0000u;
    float l = a - __uint_as_float(rh);
    unsigned v = __float_as_uint(l);
    unsigned rl = (v + 0x7FFFu + ((v >> 16) & 1u)) >> 16;
    return make_uint2(rh >> 16, rl);
}

// ---------------------------------------------------------------------------
// K1: proj weights: split-bf16 B' [NPAD][KP] + permuted bias
__global__ void wtrans_kernel(const float* __restrict__ W, const float* __restrict__ b1,
                              unsigned* __restrict__ Btg, float* __restrict__ b1p) {
    int e = blockIdx.x;
    int j = threadIdx.x;
    if (j >= NPAD) return;
    float w = 0.f;
    if (j < G4) w = W[((j & 3) * 50 + (j >> 2)) * EE + e];
    uint2 s = bfsplit(w);
    *(uint2*)(Btg + (size_t)j * KPD + 2 * e) =
        make_uint2(s.x | (s.x << 16), s.y | (s.y << 16));
    if (e == 0) b1p[j] = (j < G4) ? b1[(j & 3) * 50 + (j >> 2)] : 0.f;
}

// ---------------------------------------------------------------------------
// K2: MFMA proj (R16-verified: absmax 4.8e-7, ~85us, 0 bank conflicts).
__global__ __launch_bounds__(256, 2) void proj_kernel(
    const int* __restrict__ x, const int* __restrict__ lengths,
    const float* __restrict__ emb, const unsigned* __restrict__ Btg,
    const float* __restrict__ b1p, float* __restrict__ G1, int b0)
{
    const int b  = b0 + blockIdx.y;
    const int t0 = blockIdx.x * 64;
    const int len = lengths[b];
    if (t0 >= len) return;

    const int tid  = threadIdx.x;
    const int wv   = tid >> 6;
    const int lane = tid & 63;

    __shared__ __align__(16) char lds[2 * BUFB];

    const int arow = tid >> 2;
    const int ag   = tid & 3;
    const float* er = emb + (size_t)x[b * TT + t0 + arow] * EE;

    float4v acc[NT] = {};

    auto stageB = [&](int c, int q) {
        char* base = lds + q * BUFB + BOFF;
        #pragma unroll
        for (int rr = 0; rr < 7; ++rr) {
            if (rr < 6 || tid < 128) {
                int g   = rr * 256 + tid;
                int row = g >> 3, sl = g & 7;
                const unsigned* src = Btg + (size_t)row * KPD + c * KCD
                                      + ((sl ^ (row & 7)) << 2);
                char* dst = base + (rr * 256 + (tid & ~63)) * 16;
                __builtin_amdgcn_global_load_lds(
                    (const __attribute__((address_space(1))) void*)src,
                    (__attribute__((address_space(3))) void*)dst, 16, 0, 0);
            }
        }
    };
    auto loadA = [&](int cc) -> float4 {
        int k0 = cc * 16 + ag * 4;
        if (k0 < EE) return *(const float4*)(er + k0);
        return make_float4(0.f, 0.f, 0.f, 0.f);
    };
    auto writeA = [&](int q, float4 av) {
        uint2 s0 = bfsplit(av.x), s1 = bfsplit(av.y);
        uint2 s2 = bfsplit(av.z), s3 = bfsplit(av.w);
        unsigned p0 = s0.x | (s0.y << 16), p1 = s1.x | (s1.y << 16);
        unsigned p2 = s2.x | (s2.y << 16), p3 = s3.x | (s3.y << 16);
        char* base = lds + q * BUFB + (arow << 7);
        int r7 = arow & 7;
        *(uint4v*)(base + ((( 2 * ag    ) ^ r7) << 4)) = uint4v{p0, p0, p1, p1};
        *(uint4v*)(base + (((2 * ag + 1) ^ r7) << 4)) = uint4v{p2, p2, p3, p3};
    };

    stageB(0, 0);
    float4 aval = loadA(0);
    asm volatile("s_waitcnt vmcnt(0)" ::: "memory");
    writeA(0, aval);
    asm volatile("s_waitcnt lgkmcnt(0)" ::: "memory");
    __builtin_amdgcn_s_barrier();
    __builtin_amdgcn_sched_barrier(0);

    int p = 0;
    for (int c = 0; c < NCH; ++c) {
        const int q = p ^ 1;
        if (c + 1 < NCH) {
            stageB(c + 1, q);
            aval = loadA(c + 1);
        }
        const int r  = lane & 15;
        const int h  = lane >> 4;
        #pragma unroll
        for (int s = 0; s < 2; ++s) {
            const int sw4 = (((4 * s + h) ^ (r & 7)) << 4);
            short8v aF = *(const short8v*)(lds + p * BUFB + ((wv * 16 + r) << 7) + sw4);
            #pragma unroll
            for (int nt = 0; nt < NT; ++nt) {
                short8v bF = *(const short8v*)(lds + p * BUFB + BOFF
                                               + ((nt * 16 + r) << 7) + sw4);
                acc[nt] = __builtin_amdgcn_mfma_f32_16x16x32_bf16(aF, bF, acc[nt], 0, 0, 0);
            }
        }
        if (c + 1 < NCH) {
            asm volatile("s_waitcnt vmcnt(0)" ::: "memory");
            writeA(q, aval);
            asm volatile("s_waitcnt lgkmcnt(0)" ::: "memory");
            __builtin_amdgcn_s_barrier();
            __builtin_amdgcn_sched_barrier(0);
        }
        p = q;
    }

    float* gbase = G1 + ((size_t)blockIdx.y * TT + t0) * G4;
    const int col = lane & 15, rq = lane >> 4;
    #pragma unroll
    for (int nt = 0; nt < NT; ++nt) {
        int jp = nt * 16 + col;
        if (jp < G4) {
            float bias = b1p[jp];
            #pragma unroll
            for (int rr = 0; rr < 4; ++rr)
                gbase[(size_t)(wv * 16 + rq * 4 + rr) * G4 + jp] = acc[nt][rr] + bias;
        }
    }
}

// ---------------------------------------------------------------------------
// K3: recurrence — R16-verified 8-wave half-dot structure (227us).
// 8-lane group = one unit: sub=tid&7 -> gate g=sub&3, half=sub>>2.
__global__ __launch_bounds__(512, 1) void lstm_kernel(
    const int* __restrict__ lengths,
    const float* __restrict__ W_hh1, const float* __restrict__ W_ih2,
    const float* __restrict__ W_hh2, const float* __restrict__ b2,
    const float* __restrict__ fc1w, const float* __restrict__ fc1b,
    const float* __restrict__ fc2w, const float* __restrict__ fc2b,
    const float* __restrict__ G1, float* __restrict__ out, int b0)
{
    const int bb  = blockIdx.x;
    const int b   = b0 + bb;
    const int tid = threadIdx.x;
    const int len = lengths[b];

    __shared__ __align__(16) float hs[2][72];
    __shared__ __align__(16) float hfin[12];
    __shared__ float zbuf[10];

    if (tid < 72) { hs[0][tid] = 0.f; hs[1][tid] = 0.f; }

    const bool isL1 = (tid < 400);
    const bool isL2 = (tid >= 400 && tid < 480);
    const int  grp  = tid >> 3;
    const int  sub  = tid & 7;
    const int  g    = sub & 3;
    const int  half = sub >> 2;

    float wreg[28];
    float wregb[12];
    #pragma unroll
    for (int k = 0; k < 28; ++k) wreg[k] = 0.f;
    #pragma unroll
    for (int k = 0; k < 12; ++k) wregb[k] = 0.f;
    float base2 = 0.f;

    if (isL1) {
        int row = g * 50 + grp;
        const float* wp = W_hh1 + row * 50 + half * 28;
        int n = half ? 22 : 28;
        for (int k = 0; k < 28; ++k) wreg[k] = (k < n) ? wp[k] : 0.f;
    } else if (isL2) {
        int u = grp - 50;
        int row = g * 10 + u;
        const float* wp = W_ih2 + row * 50 + half * 28;
        int n = half ? 22 : 28;
        for (int k = 0; k < 28; ++k) wreg[k] = (k < n) ? wp[k] : 0.f;
        if (half == 0) {
            const float* wp2 = W_hh2 + row * 10;
            #pragma unroll
            for (int k = 0; k < 10; ++k) wregb[k] = wp2[k];
            base2 = b2[row];
        }
    }
    #pragma unroll
    for (int k = 0; k < 28; ++k) asm volatile("" : "+v"(wreg[k]));
    #pragma unroll
    for (int k = 0; k < 12; ++k) asm volatile("" : "+v"(wregb[k]));
    asm volatile("" : "+v"(base2));

    const bool gld  = isL1 && (half == 0);
    const int  gcol = gld ? (4 * grp + g) : 0;
    const bool wr   = (sub == 0) && (tid < 480);
    const int  slot = isL1 ? grp : (56 + grp - 50);

    float h1v[28], h2v[12];
    #pragma unroll
    for (int k = 0; k < 28; ++k) h1v[k] = 0.f;
    #pragma unroll
    for (int k = 0; k < 12; ++k) h2v[k] = 0.f;

    float c = 0.f;
    const float* g1p = G1 + (size_t)bb * TT * G4;
    float p0 = 0.f, p1 = 0.f, p2 = 0.f;
    if (gld) {
        int t1 = (1 < len) ? 1 : len - 1;
        int t2 = (2 < len) ? 2 : len - 1;
        p0 = g1p[gcol];
        p1 = g1p[(size_t)t1 * G4 + gcol];
        p2 = g1p[(size_t)t2 * G4 + gcol];
    }

    __syncthreads();

    for (int i = 0; i < len; ++i) {
        float base = gld ? p0 : ((isL2 && half == 0) ? base2 : 0.f);
        p0 = p1; p1 = p2;
        if (gld) {
            int tn = (i + 3 < len) ? i + 3 : len - 1;
            p2 = g1p[(size_t)tn * G4 + gcol];
        }

        float s0 = 0.f, s1 = 0.f, s2 = 0.f, s3 = 0.f;
        #pragma unroll
        for (int m = 0; m < 7; ++m) {
            s0 = fmaf(wreg[4*m+0], h1v[4*m+0], s0);
            s1 = fmaf(wreg[4*m+1], h1v[4*m+1], s1);
            s2 = fmaf(wreg[4*m+2], h1v[4*m+2], s2);
            s3 = fmaf(wreg[4*m+3], h1v[4*m+3], s3);
        }
        #pragma unroll
        for (int m = 0; m < 3; ++m) {
            s0 = fmaf(wregb[4*m+0], h2v[4*m+0], s0);
            s1 = fmaf(wregb[4*m+1], h2v[4*m+1], s1);
            s2 = fmaf(wregb[4*m+2], h2v[4*m+2], s2);
            s3 = fmaf(wregb[4*m+3], h2v[4*m+3], s3);
        }
        float t = base + (s0 + s1) + (s2 + s3);
        float full = xor4_sum(t, half);

        float gi = qb<0x00>(full);
        float gf = qb<0x55>(full);
        float gg = qb<0xAA>(full);
        float go = qb<0xFF>(full);
        float cn = sigm(gf) * c + sigm(gi) * tanh_(gg);
        float hn = sigm(go) * tanh_(cn);
        if (isL2 && i == 0) { cn = 0.f; hn = 0.f; }
        c = cn;
        if (wr) hs[i & 1][slot] = hn;

        asm volatile("s_waitcnt lgkmcnt(0)" ::: "memory");
        __builtin_amdgcn_s_barrier();
        __builtin_amdgcn_sched_barrier(0);

        const float* hb = hs[i & 1] + half * 28;
        #pragma unroll
        for (int m = 0; m < 7; ++m) {
            float4 v = *(const float4*)(hb + 4 * m);
            h1v[4*m+0] = v.x; h1v[4*m+1] = v.y;
            h1v[4*m+2] = v.z; h1v[4*m+3] = v.w;
        }
        if (tid >= 384) {
            const float* hb2 = hs[i & 1] + 56;
            #pragma unroll
            for (int m = 0; m < 3; ++m) {
                float4 v = *(const float4*)(hb2 + 4 * m);
                h2v[4*m+0] = v.x; h2v[4*m+1] = v.y;
                h2v[4*m+2] = v.z; h2v[4*m+3] = v.w;
            }
        }
    }

    {
        float s0 = 0.f, s1 = 0.f, s2 = 0.f, s3 = 0.f;
        #pragma unroll
        for (int m = 0; m < 7; ++m) {
            s0 = fmaf(wreg[4*m+0], h1v[4*m+0], s0);
            s1 = fmaf(wreg[4*m+1], h1v[4*m+1], s1);
            s2 = fmaf(wreg[4*m+2], h1v[4*m+2], s2);
            s3 = fmaf(wreg[4*m+3], h1v[4*m+3], s3);
        }
        #pragma unroll
        for (int m = 0; m < 3; ++m) {
            s0 = fmaf(wregb[4*m+0], h2v[4*m+0], s0);
            s1 = fmaf(wregb[4*m+1], h2v[4*m+1], s1);
            s2 = fmaf(wregb[4*m+2], h2v[4*m+2], s2);
            s3 = fmaf(wregb[4*m+3], h2v[4*m+3], s3);
        }
        float t = ((isL2 && half == 0) ? base2 : 0.f) + (s0 + s1) + (s2 + s3);
        float full = xor4_sum(t, half);
        float gi = qb<0x00>(full);
        float gf = qb<0x55>(full);
        float gg = qb<0xAA>(full);
        float go = qb<0xFF>(full);
        float cn = sigm(gf) * c + sigm(gi) * tanh_(gg);
        float hn = sigm(go) * tanh_(cn);
        if (isL2 && sub == 0) hfin[grp - 50] = hn;
    }
    __syncthreads();

    if (tid < 10) {
        float s = fc1b[tid];
        #pragma unroll
        for (int e = 0; e < 10; ++e) s = fmaf(fc1w[tid * 10 + e], hfin[e], s);
        zbuf[tid] = s > 0.f ? s : 0.f;
    }
    __syncthreads();
    if (tid == 0) {
        float s = fc2b[0];
        #pragma unroll
        for (int e = 0; e < 10; ++e) s = fmaf(fc2w[e], zbuf[e], s);
        out[b] = s;
    }
}

// ---------------------------------------------------------------------------
extern "C" void kernel_launch(void* const* d_in, const int* in_sizes, int n_in,
                              void* d_out, int out_size, void* d_ws, size_t ws_size,
                              hipStream_t stream)
{
    const int*   x     = (const int*)  d_in[0];
    const int*   len   = (const int*)  d_in[1];
    const float* emb   = (const float*)d_in[2];
    const float* W_ih1 = (const float*)d_in[3];
    const float* W_hh1 = (const float*)d_in[4];
    const float* b1    = (const float*)d_in[5];
    const float* W_ih2 = (const float*)d_in[6];
    const float* W_hh2 = (const float*)d_in[7];
    const float* b2    = (const float*)d_in[8];
    const float* fc1w  = (const float*)d_in[9];
    const float* fc1b  = (const float*)d_in[10];
    const float* fc2w  = (const float*)d_in[11];
    const float* fc2b  = (const float*)d_in[12];
    float* out = (float*)d_out;

    const size_t btg_bytes = (size_t)NPAD * KPD * sizeof(unsigned);   // 505856
    const size_t b1p_off = btg_bytes;
    const size_t head = (b1p_off + NPAD * sizeof(float) + 255) & ~255ull;
    const size_t per_b = (size_t)TT * G4 * sizeof(float);             // 409600

    unsigned* Btg = (unsigned*)d_ws;
    float*    b1p = (float*)((char*)d_ws + b1p_off);
    float*    G1  = (float*)((char*)d_ws + head);

    size_t avail = ws_size > head ? ws_size - head : 0;
    int chunk = (int)(avail / per_b);
    if (chunk < 1) chunk = 1;
    if (chunk > BB) chunk = BB;

    wtrans_kernel<<<dim3(EE), dim3(256), 0, stream>>>(W_ih1, b1, Btg, b1p);

    for (int b0 = 0; b0 < BB; b0 += chunk) {
        int nb = (BB - b0) < chunk ? (BB - b0) : chunk;
        proj_kernel<<<dim3(TT / 64, nb), dim3(256), 0, stream>>>(
            x, len, emb, Btg, b1p, G1, b0);
        lstm_kernel<<<dim3(nb), dim3(512), 0, stream>>>(
            len, W_hh1, W_ih2, W_hh2, b2, fc1w, fc1b, fc2w, fc2b, G1, out, b0);
    }
}